// Round 2
// baseline (1054.184 us; speedup 1.0000x reference)
//
#include <hip/hip_runtime.h>
#include <hip/hip_bf16.h>

// Problem constants (fixed by the reference)
constexpr int BATCH  = 32;
constexpr int TIME   = 1024;
constexpr int IN_DIM = 512;
constexpr int HIDDEN = 512;

constexpr int GM = BATCH * TIME;   // 32768  (GEMM M)
constexpr int GN = HIDDEN;         // 512    (GEMM N)
constexpr int GK = IN_DIM;         // 512    (GEMM K)

// ---------------- Phase 1: fp32 SGEMM with bias ----------------
// 128x128x16 tile, 256 threads, 8x8 microtile, DOUBLE-BUFFERED LDS:
// one barrier per K-tile; next tile's global loads issue right after the
// barrier and land in LDS one iteration later (full-tile latency hiding).
constexpr int BM = 128;
constexpr int BN = 128;
constexpr int BK = 16;
constexpr int LDAs = BM + 4;   // padded leading dims (floats)
constexpr int LDBs = BN + 4;

__global__ __launch_bounds__(256, 4) void sgemm_bias_kernel(
    const float* __restrict__ A,     // [GM, GK]
    const float* __restrict__ B,     // [GK, GN]
    const float* __restrict__ bias,  // [GN]
    float* __restrict__ C)           // [GM, GN]
{
    __shared__ __align__(16) float As[2][BK * LDAs];
    __shared__ __align__(16) float Bs[2][BK * LDBs];

    const int tid = threadIdx.x;           // 0..255
    // blockIdx.x = M-tile (256 of them), blockIdx.y = N-tile (4).
    // Same-M blocks (sharing A rows) are 256 apart in linear block id ->
    // same XCD under round-robin dispatch -> A fetched once per XCD.
    const int bm  = blockIdx.x * BM;
    const int bn  = blockIdx.y * BN;

    // wave-quadrant mapping: wave w covers a 64x64 quadrant; within the wave
    // lanes form an 8x8 grid -> LDS frag reads are 2-way aliased (free).
    const int w    = tid >> 6;
    const int lane = tid & 63;
    const int row0 = (w >> 1) * 64 + (lane >> 3) * 8;
    const int col0 = (w & 1)  * 64 + (lane & 7)  * 8;

    // per-thread global-load coordinates (two float4 quads each for A and B)
    const int ar0 = tid >> 2;              // A row for quad 0 (0..63)
    const int ac  = (tid & 3) << 2;        // A col within K-tile (0..12)
    const int br0 = tid >> 5;              // B row for quad 0 (0..7)
    const int bc  = (tid & 31) << 2;       // B col within N-tile (0..124)

    float4 va[2], vb[2];

    auto load_tile = [&](int k0) {
        va[0] = *reinterpret_cast<const float4*>(A + (size_t)(bm + ar0) * GK + k0 + ac);
        va[1] = *reinterpret_cast<const float4*>(A + (size_t)(bm + ar0 + 64) * GK + k0 + ac);
        vb[0] = *reinterpret_cast<const float4*>(B + (size_t)(k0 + br0) * GN + bn + bc);
        vb[1] = *reinterpret_cast<const float4*>(B + (size_t)(k0 + br0 + 8) * GN + bn + bc);
    };

    float acc[8][8];
    #pragma unroll
    for (int i = 0; i < 8; ++i)
        #pragma unroll
        for (int j = 0; j < 8; ++j) acc[i][j] = 0.0f;

    load_tile(0);

    constexpr int NTILES = GK / BK;        // 32
    #pragma unroll 1
    for (int it = 0; it < NTILES; ++it) {
        const int p = it & 1;
        float* asp = As[p];
        float* bsp = Bs[p];

        // ---- stage prefetched regs into LDS buffer p ----
        {
            asp[(ac + 0) * LDAs + ar0] = va[0].x;
            asp[(ac + 1) * LDAs + ar0] = va[0].y;
            asp[(ac + 2) * LDAs + ar0] = va[0].z;
            asp[(ac + 3) * LDAs + ar0] = va[0].w;
            asp[(ac + 0) * LDAs + ar0 + 64] = va[1].x;
            asp[(ac + 1) * LDAs + ar0 + 64] = va[1].y;
            asp[(ac + 2) * LDAs + ar0 + 64] = va[1].z;
            asp[(ac + 3) * LDAs + ar0 + 64] = va[1].w;
            *reinterpret_cast<float4*>(&bsp[br0 * LDBs + bc]) = vb[0];
            *reinterpret_cast<float4*>(&bsp[(br0 + 8) * LDBs + bc]) = vb[1];
        }

        __syncthreads();

        // ---- issue next tile's global loads (consumed next iteration) ----
        if (it + 1 < NTILES) load_tile((it + 1) * BK);

        // ---- compute 16 k-steps from buffer p ----
        #pragma unroll
        for (int kk = 0; kk < BK; ++kk) {
            const float4 a0 = *reinterpret_cast<const float4*>(&asp[kk * LDAs + row0]);
            const float4 a1 = *reinterpret_cast<const float4*>(&asp[kk * LDAs + row0 + 4]);
            const float4 b0 = *reinterpret_cast<const float4*>(&bsp[kk * LDBs + col0]);
            const float4 b1 = *reinterpret_cast<const float4*>(&bsp[kk * LDBs + col0 + 4]);
            const float arr[8] = {a0.x, a0.y, a0.z, a0.w, a1.x, a1.y, a1.z, a1.w};
            const float brr[8] = {b0.x, b0.y, b0.z, b0.w, b1.x, b1.y, b1.z, b1.w};
            #pragma unroll
            for (int i = 0; i < 8; ++i)
                #pragma unroll
                for (int j = 0; j < 8; ++j)
                    acc[i][j] = fmaf(arr[i], brr[j], acc[i][j]);
        }
    }

    // ---- epilogue: add bias (separate fp32 add, like numpy), store ----
    #pragma unroll
    for (int i = 0; i < 8; ++i) {
        const size_t r = (size_t)(bm + row0 + i);
        #pragma unroll
        for (int j = 0; j < 8; j += 4) {
            float4 v;
            v.x = __fadd_rn(acc[i][j + 0], bias[bn + col0 + j + 0]);
            v.y = __fadd_rn(acc[i][j + 1], bias[bn + col0 + j + 1]);
            v.z = __fadd_rn(acc[i][j + 2], bias[bn + col0 + j + 2]);
            v.w = __fadd_rn(acc[i][j + 3], bias[bn + col0 + j + 3]);
            *reinterpret_cast<float4*>(&C[r * GN + bn + col0 + j]) = v;
        }
    }
}

// ---------------- Phase 2: sequential LIF scan ----------------
// One thread per (b,h). Chunk=32 timesteps, software-pipelined: chunk c+1's
// 32 loads issue before chunk c's compute -> up to 64 loads in flight per
// thread (256 waves x 64 x 256B = 4 MB in flight; BW*latency needs ~2.4 MB).
constexpr int CH = 32;                     // chunk length
constexpr int NCH = TIME / CH;             // 32 chunks

__global__ __launch_bounds__(64) void lif_scan_kernel(
    const float* __restrict__ I,   // [B, T, H]
    float* __restrict__ O)         // [B, T, H]
{
    const int idx = blockIdx.x * 64 + threadIdx.x;   // 0..16383
    const int b = idx >> 9;
    const int h = idx & 511;

    const size_t base = (size_t)b * TIME * HIDDEN + h;
    const float* Ip = I + base;
    float*       Op = O + base;

    // exp(-0.05), exp(-0.2) correctly rounded fp32 (match np.exp)
    const float am = 0.95122942450071400910f;
    const float as = 0.81873075307798185867f;

    float v = 0.0f, s = 0.0f;
    float bufA[CH], bufB[CH];

    // prologue: load chunk 0 into bufA
    #pragma unroll
    for (int u = 0; u < CH; ++u)
        bufA[u] = Ip[(size_t)u * HIDDEN];

    #pragma unroll 1
    for (int c = 0; c < NCH; c += 2) {
        // prefetch chunk c+1 (always exists: c <= NCH-2)
        #pragma unroll
        for (int u = 0; u < CH; ++u)
            bufB[u] = Ip[(size_t)((c + 1) * CH + u) * HIDDEN];

        // compute + store chunk c from bufA
        {
            float ob[CH];
            #pragma unroll
            for (int u = 0; u < CH; ++u) {
                s = __fadd_rn(__fmul_rn(as, s), bufA[u]);
                v = __fadd_rn(__fmul_rn(am, v), s);
                const float o = (v > 1.0f) ? 1.0f : 0.0f;
                v = __fsub_rn(v, o);
                ob[u] = o;
            }
            #pragma unroll
            for (int u = 0; u < CH; ++u)
                Op[(size_t)(c * CH + u) * HIDDEN] = ob[u];
        }

        // prefetch chunk c+2 into bufA (guarded, wave-uniform branch)
        if (c + 2 < NCH) {
            #pragma unroll
            for (int u = 0; u < CH; ++u)
                bufA[u] = Ip[(size_t)((c + 2) * CH + u) * HIDDEN];
        }

        // compute + store chunk c+1 from bufB
        {
            float ob[CH];
            #pragma unroll
            for (int u = 0; u < CH; ++u) {
                s = __fadd_rn(__fmul_rn(as, s), bufB[u]);
                v = __fadd_rn(__fmul_rn(am, v), s);
                const float o = (v > 1.0f) ? 1.0f : 0.0f;
                v = __fsub_rn(v, o);
                ob[u] = o;
            }
            #pragma unroll
            for (int u = 0; u < CH; ++u)
                Op[(size_t)((c + 1) * CH + u) * HIDDEN] = ob[u];
        }
    }
}

extern "C" void kernel_launch(void* const* d_in, const int* in_sizes, int n_in,
                              void* d_out, int out_size, void* d_ws, size_t ws_size,
                              hipStream_t stream) {
    const float* spikes = (const float*)d_in[0];   // [32, 1024, 512]
    const float* W      = (const float*)d_in[1];   // [512, 512]
    const float* bias   = (const float*)d_in[2];   // [512]
    float* out  = (float*)d_out;                   // [32, 1024, 512]
    float* I_in = (float*)d_ws;                    // 64 MiB scratch

    dim3 g1(GM / BM, GN / BN);                     // (256, 4)
    sgemm_bias_kernel<<<g1, 256, 0, stream>>>(spikes, W, bias, I_in);

    lif_scan_kernel<<<BATCH * HIDDEN / 64, 64, 0, stream>>>(I_in, out);
}

// Round 3
// 472.635 us; speedup vs baseline: 2.2304x; 2.2304x over previous
//
#include <hip/hip_runtime.h>
#include <hip/hip_bf16.h>

// Problem constants (fixed by the reference)
constexpr int BATCH  = 32;
constexpr int TIME   = 1024;
constexpr int IN_DIM = 512;
constexpr int HIDDEN = 512;

constexpr int GM = BATCH * TIME;   // 32768  (GEMM M)
constexpr int GN = HIDDEN;         // 512    (GEMM N)
constexpr int GK = IN_DIM;         // 512    (GEMM K)

#define GLOBAL_AS __attribute__((address_space(1)))
#define LDS_AS    __attribute__((address_space(3)))

// s_waitcnt immediate: vmcnt[3:0]|expcnt(no-wait)|lgkmcnt(no-wait)|vmcnt[5:4]
#define WAITCNT_VMCNT(n) (((n) & 15) | (((n) >> 4) << 14) | (0x7 << 4) | (0xF << 8))

// ---------------- Phase 1: fp32 SGEMM with bias ----------------
// 128x128x16 tile, 256 threads, 8x8 microtile.
// Pipeline: prefetch tile i+1 (A->regs, B->LDS async) BEFORE compute of
// tile i; A regs staged to LDS after compute; ONE barrier per tile.
// NOTE: plain __launch_bounds__(256). (256,4) in round 2 capped VGPRs at 64
// and spilled the 64-float accumulator -> 4.5 GB scratch traffic. Never
// force min-occupancy on a 64-acc kernel.
constexpr int BM = 128;
constexpr int BN = 128;
constexpr int BK = 16;
constexpr int LDAs = BM + 4;   // A^T in LDS (padded; 2-way conflicts only)
// Bs stride is exactly BN (128): required by global_load_lds's
// wave-uniform-base + lane*4 destination layout (no padding allowed).

__global__ __launch_bounds__(256) void sgemm_bias_kernel(
    const float* __restrict__ A,     // [GM, GK]
    const float* __restrict__ B,     // [GK, GN]
    const float* __restrict__ bias,  // [GN]
    float* __restrict__ C)           // [GM, GN]
{
    __shared__ __align__(16) float As[2][BK * LDAs];
    __shared__ __align__(16) float Bs[2][BK * BN];

    const int tid = threadIdx.x;           // 0..255
    // blockIdx.x = M-tile (256), blockIdx.y = N-tile (4): same-A blocks are
    // 256 apart in linear id -> same XCD under round-robin -> A L2 reuse.
    const int bm  = blockIdx.x * BM;
    const int bn  = blockIdx.y * BN;

    const int wave = tid >> 6;
    const int lane = tid & 63;
    const int row0 = (wave >> 1) * 64 + (lane >> 3) * 8;
    const int col0 = (wave & 1)  * 64 + (lane & 7)  * 8;

    // A global-load coords: two float4 per thread
    const int ar0 = tid >> 2;              // 0..63 (and +64)
    const int ac  = (tid & 3) << 2;        // 0,4,8,12

    float4 va0, va1;

    auto load_a = [&](int k0) {
        va0 = *reinterpret_cast<const float4*>(A + (size_t)(bm + ar0) * GK + k0 + ac);
        va1 = *reinterpret_cast<const float4*>(A + (size_t)(bm + ar0 + 64) * GK + k0 + ac);
    };
    auto store_a = [&](float* asp) {
        asp[(ac + 0) * LDAs + ar0] = va0.x;
        asp[(ac + 1) * LDAs + ar0] = va0.y;
        asp[(ac + 2) * LDAs + ar0] = va0.z;
        asp[(ac + 3) * LDAs + ar0] = va0.w;
        asp[(ac + 0) * LDAs + ar0 + 64] = va1.x;
        asp[(ac + 1) * LDAs + ar0 + 64] = va1.y;
        asp[(ac + 2) * LDAs + ar0 + 64] = va1.z;
        asp[(ac + 3) * LDAs + ar0 + 64] = va1.w;
    };
    // B tile = 16 rows x 128 floats = 32 segments of 256B; wave w issues
    // segments w*8 .. w*8+7 as async DMA (64 lanes x 4B each).
    auto load_b_async = [&](int k0, float* bsp) {
        #pragma unroll
        for (int j = 0; j < 8; ++j) {
            const int s = wave * 8 + j;
            const int r = s >> 1;               // 0..15
            const int c = (s & 1) * 64;         // 0 or 64
            const float* g = B + (size_t)(k0 + r) * GN + bn + c + lane;
            __builtin_amdgcn_global_load_lds(
                (GLOBAL_AS const void*)g,
                (LDS_AS void*)&bsp[r * BN + c], 4, 0, 0);
        }
    };

    float acc[8][8];
    #pragma unroll
    for (int i = 0; i < 8; ++i)
        #pragma unroll
        for (int j = 0; j < 8; ++j) acc[i][j] = 0.0f;

    // ---- prologue: tile 0 ----
    load_a(0);
    load_b_async(0, Bs[0]);
    store_a(As[0]);            // compiler waits vmcnt for va only
    __syncthreads();           // drains vmcnt(0): B DMA + A stores visible

    constexpr int NTILES = GK / BK;        // 32
    #pragma unroll 1
    for (int it = 0; it < NTILES; ++it) {
        const int p = it & 1;
        float* asp = As[p];
        float* bsp = Bs[p];
        const bool more = (it + 1 < NTILES);

        // ---- issue prefetch for tile i+1 (hidden behind compute) ----
        if (more) {
            load_a((it + 1) * BK);
            load_b_async((it + 1) * BK, Bs[1 - p]);
        }

        // ---- compute 16 k-steps from buffer p ----
        #pragma unroll
        for (int kk = 0; kk < BK; ++kk) {
            const float4 a0 = *reinterpret_cast<const float4*>(&asp[kk * LDAs + row0]);
            const float4 a1 = *reinterpret_cast<const float4*>(&asp[kk * LDAs + row0 + 4]);
            const float4 b0 = *reinterpret_cast<const float4*>(&bsp[kk * BN + col0]);
            const float4 b1 = *reinterpret_cast<const float4*>(&bsp[kk * BN + col0 + 4]);
            const float arr[8] = {a0.x, a0.y, a0.z, a0.w, a1.x, a1.y, a1.z, a1.w};
            const float brr[8] = {b0.x, b0.y, b0.z, b0.w, b1.x, b1.y, b1.z, b1.w};
            #pragma unroll
            for (int i = 0; i < 8; ++i)
                #pragma unroll
                for (int j = 0; j < 8; ++j)
                    acc[i][j] = fmaf(arr[i], brr[j], acc[i][j]);
        }

        if (more) {
            store_a(As[1 - p]);    // waits vmcnt for va (B DMA still in flight)
            __syncthreads();       // drains the rest (long since landed)
        }
    }

    // ---- epilogue: add bias (separate fp32 add, like numpy), store ----
    #pragma unroll
    for (int i = 0; i < 8; ++i) {
        const size_t r = (size_t)(bm + row0 + i);
        #pragma unroll
        for (int j = 0; j < 8; j += 4) {
            float4 v;
            v.x = __fadd_rn(acc[i][j + 0], bias[bn + col0 + j + 0]);
            v.y = __fadd_rn(acc[i][j + 1], bias[bn + col0 + j + 1]);
            v.z = __fadd_rn(acc[i][j + 2], bias[bn + col0 + j + 2]);
            v.w = __fadd_rn(acc[i][j + 3], bias[bn + col0 + j + 3]);
            *reinterpret_cast<float4*>(&C[r * GN + bn + col0 + j]) = v;
        }
    }
}

// ---------------- Phase 2: LIF scan, producer/consumer waves ----------------
// Round-1/2 scan measured ~104 us => effective MLP ~7 loads/wave (compiler
// would not keep 32 in flight). Fix: wave 0 streams I_in into a 128 KB LDS
// ring via async global_load_lds with EXPLICIT s_waitcnt vmcnt(32) group
// retirement -> 32..64 loads always outstanding per block x 256 blocks
// = 2..4 MB in flight (>= BW*latency product). Wave 1 runs the recurrence
// from LDS, gated by an LDS progress counter.
constexpr int SCH    = 32;                 // timesteps per chunk
constexpr int NCHK   = TIME / SCH;         // 32 chunks
constexpr int RING_T = 512;                // ring capacity in timesteps
constexpr int RINGC  = RING_T / SCH;       // 16 ring chunks

__global__ __launch_bounds__(128) void lif_scan_kernel(
    const float* __restrict__ I,   // [B, T, H]
    float* __restrict__ O)         // [B, T, H]
{
    __shared__ float ring[RING_T * 64];    // 128 KB
    __shared__ int prod_c;                 // chunks fully landed in LDS
    __shared__ int cons_c;                 // chunks consumed

    const int blk  = blockIdx.x;           // 0..255
    const int b    = blk >> 3;             // 8 blocks per batch row
    const int h0   = (blk & 7) * 64;
    const int wave = threadIdx.x >> 6;
    const int lane = threadIdx.x & 63;
    const size_t base = (size_t)b * TIME * HIDDEN + h0;

    if (threadIdx.x == 0) { prod_c = 0; cons_c = 0; }
    __syncthreads();

    if (wave == 0) {
        // ---------------- producer ----------------
        const float* g0 = I + base + lane;
        #pragma unroll 1
        for (int c = 0; c < NCHK; ++c) {
            if (c >= RINGC) {   // backpressure: don't overwrite live slot
                while (__hip_atomic_load(&cons_c, __ATOMIC_ACQUIRE,
                                         __HIP_MEMORY_SCOPE_WORKGROUP)
                       <= c - RINGC) { }
            }
            const int slot = (c & (RINGC - 1)) * SCH;
            #pragma unroll
            for (int u = 0; u < SCH; ++u) {
                const int t = c * SCH + u;
                __builtin_amdgcn_global_load_lds(
                    (GLOBAL_AS const void*)(g0 + (size_t)t * HIDDEN),
                    (LDS_AS void*)&ring[(slot + u) * 64], 4, 0, 0);
            }
            // all but the newest 32 loads have landed => chunks <= c-1 done
            __builtin_amdgcn_s_waitcnt(WAITCNT_VMCNT(32));
            __hip_atomic_store(&prod_c, c, __ATOMIC_RELEASE,
                               __HIP_MEMORY_SCOPE_WORKGROUP);
        }
        __builtin_amdgcn_s_waitcnt(WAITCNT_VMCNT(0));
        __hip_atomic_store(&prod_c, NCHK, __ATOMIC_RELEASE,
                           __HIP_MEMORY_SCOPE_WORKGROUP);
    } else {
        // ---------------- consumer ----------------
        // exp(-0.05), exp(-0.2) correctly rounded fp32 (match np.exp)
        const float am = 0.95122942450071400910f;
        const float as = 0.81873075307798185867f;
        float v = 0.0f, s = 0.0f;
        float* o0 = O + base + lane;

        #pragma unroll 1
        for (int c = 0; c < NCHK; ++c) {
            while (__hip_atomic_load(&prod_c, __ATOMIC_ACQUIRE,
                                     __HIP_MEMORY_SCOPE_WORKGROUP) < c + 1) { }
            const int slot = (c & (RINGC - 1)) * SCH;
            float ob[SCH];
            #pragma unroll
            for (int u = 0; u < SCH; ++u) {
                const float x = ring[(slot + u) * 64 + lane];
                // separate mul/add roundings to match numpy (no FMA fusion)
                s = __fadd_rn(__fmul_rn(as, s), x);
                v = __fadd_rn(__fmul_rn(am, v), s);
                const float o = (v > 1.0f) ? 1.0f : 0.0f;
                v = __fsub_rn(v, o);
                ob[u] = o;
            }
            #pragma unroll
            for (int u = 0; u < SCH; ++u)
                o0[(size_t)(c * SCH + u) * HIDDEN] = ob[u];
            __hip_atomic_store(&cons_c, c + 1, __ATOMIC_RELEASE,
                               __HIP_MEMORY_SCOPE_WORKGROUP);
        }
    }
}

extern "C" void kernel_launch(void* const* d_in, const int* in_sizes, int n_in,
                              void* d_out, int out_size, void* d_ws, size_t ws_size,
                              hipStream_t stream) {
    const float* spikes = (const float*)d_in[0];   // [32, 1024, 512]
    const float* W      = (const float*)d_in[1];   // [512, 512]
    const float* bias   = (const float*)d_in[2];   // [512]
    float* out  = (float*)d_out;                   // [32, 1024, 512]
    float* I_in = (float*)d_ws;                    // 64 MiB scratch

    dim3 g1(GM / BM, GN / BN);                     // (256, 4)
    sgemm_bias_kernel<<<g1, 256, 0, stream>>>(spikes, W, bias, I_in);

    lif_scan_kernel<<<BATCH * HIDDEN / 64, 128, 0, stream>>>(I_in, out);
}

// Round 4
// 367.952 us; speedup vs baseline: 2.8650x; 1.2845x over previous
//
#include <hip/hip_runtime.h>
#include <hip/hip_bf16.h>

// Problem constants (fixed by the reference)
constexpr int BATCH  = 32;
constexpr int TIME   = 1024;
constexpr int IN_DIM = 512;
constexpr int HIDDEN = 512;

constexpr int GM = BATCH * TIME;   // 32768  (GEMM M)
constexpr int GN = HIDDEN;         // 512    (GEMM N)
constexpr int GK = IN_DIM;         // 512    (GEMM K)

#define GLOBAL_AS __attribute__((address_space(1)))
#define LDS_AS    __attribute__((address_space(3)))

// s_waitcnt immediate: vmcnt[3:0]|expcnt(no-wait)|lgkmcnt(no-wait)|vmcnt[5:4]
#define WAITCNT_VMCNT(n) (((n) & 15) | (((n) >> 4) << 14) | (0x7 << 4) | (0xF << 8))

// ---------------- Phase 1: fp32 SGEMM with bias ----------------
// 128x128x16 tile, 256 threads, 8x8 microtile. Register double-buffer:
// per iteration: stage prefetched regs -> LDS[p]; ONE barrier; issue global
// loads for tile i+1 (land during compute); compute tile i from LDS[p].
// VGPR discipline is the whole game here (R2: (256,4) cap -> spill -> 4.5GB
// scratch; R3: async DMA addrs -> 180 VGPR -> 1 block/CU -> 385us). Plain
// loads + plain bound keep ~72-90 VGPR -> 4+ blocks/CU to hide barriers.
constexpr int BM = 128;
constexpr int BN = 128;
constexpr int BK = 16;
constexpr int LDAs = BM + 4;   // padded leading dims (floats)
constexpr int LDBs = BN + 4;

__global__ __launch_bounds__(256) void sgemm_bias_kernel(
    const float* __restrict__ A,     // [GM, GK]
    const float* __restrict__ B,     // [GK, GN]
    const float* __restrict__ bias,  // [GN]
    float* __restrict__ C)           // [GM, GN]
{
    __shared__ __align__(16) float As[2][BK * LDAs];
    __shared__ __align__(16) float Bs[2][BK * LDBs];

    const int tid = threadIdx.x;           // 0..255
    // blockIdx.x = M-tile (256), blockIdx.y = N-tile (4): same-A blocks are
    // 256 apart in linear id -> same XCD under round-robin -> A L2 reuse.
    const int bm  = blockIdx.x * BM;
    const int bn  = blockIdx.y * BN;

    // wave-quadrant mapping: wave w covers a 64x64 quadrant; within the wave
    // lanes form an 8x8 grid -> LDS frag reads are 2-way aliased (free).
    const int w    = tid >> 6;
    const int lane = tid & 63;
    const int row0 = (w >> 1) * 64 + (lane >> 3) * 8;
    const int col0 = (w & 1)  * 64 + (lane & 7)  * 8;

    // per-thread global-load coordinates (two float4 quads each for A and B)
    const int ar0 = tid >> 2;              // A row for quad 0 (0..63), +64
    const int ac  = (tid & 3) << 2;        // A col within K-tile (0..12)
    const int br0 = tid >> 5;              // B row for quad 0 (0..7), +8
    const int bc  = (tid & 31) << 2;       // B col within N-tile (0..124)

    float4 va[2], vb[2];

    auto load_tile = [&](int k0) {
        va[0] = *reinterpret_cast<const float4*>(A + (size_t)(bm + ar0) * GK + k0 + ac);
        va[1] = *reinterpret_cast<const float4*>(A + (size_t)(bm + ar0 + 64) * GK + k0 + ac);
        vb[0] = *reinterpret_cast<const float4*>(B + (size_t)(k0 + br0) * GN + bn + bc);
        vb[1] = *reinterpret_cast<const float4*>(B + (size_t)(k0 + br0 + 8) * GN + bn + bc);
    };

    float acc[8][8];
    #pragma unroll
    for (int i = 0; i < 8; ++i)
        #pragma unroll
        for (int j = 0; j < 8; ++j) acc[i][j] = 0.0f;

    load_tile(0);

    constexpr int NTILES = GK / BK;        // 32
    #pragma unroll 1
    for (int it = 0; it < NTILES; ++it) {
        const int p = it & 1;
        float* asp = As[p];
        float* bsp = Bs[p];

        // ---- stage prefetched regs into LDS buffer p ----
        // (writes to buf p can't collide with laggards reading buf 1-p)
        asp[(ac + 0) * LDAs + ar0] = va[0].x;
        asp[(ac + 1) * LDAs + ar0] = va[0].y;
        asp[(ac + 2) * LDAs + ar0] = va[0].z;
        asp[(ac + 3) * LDAs + ar0] = va[0].w;
        asp[(ac + 0) * LDAs + ar0 + 64] = va[1].x;
        asp[(ac + 1) * LDAs + ar0 + 64] = va[1].y;
        asp[(ac + 2) * LDAs + ar0 + 64] = va[1].z;
        asp[(ac + 3) * LDAs + ar0 + 64] = va[1].w;
        *reinterpret_cast<float4*>(&bsp[br0 * LDBs + bc]) = vb[0];
        *reinterpret_cast<float4*>(&bsp[(br0 + 8) * LDBs + bc]) = vb[1];

        __syncthreads();   // the ONLY barrier per tile

        // ---- issue next tile's global loads (hidden behind compute) ----
        if (it + 1 < NTILES) load_tile((it + 1) * BK);

        // ---- compute 16 k-steps from buffer p ----
        #pragma unroll
        for (int kk = 0; kk < BK; ++kk) {
            const float4 a0 = *reinterpret_cast<const float4*>(&asp[kk * LDAs + row0]);
            const float4 a1 = *reinterpret_cast<const float4*>(&asp[kk * LDAs + row0 + 4]);
            const float4 b0 = *reinterpret_cast<const float4*>(&bsp[kk * LDBs + col0]);
            const float4 b1 = *reinterpret_cast<const float4*>(&bsp[kk * LDBs + col0 + 4]);
            const float arr[8] = {a0.x, a0.y, a0.z, a0.w, a1.x, a1.y, a1.z, a1.w};
            const float brr[8] = {b0.x, b0.y, b0.z, b0.w, b1.x, b1.y, b1.z, b1.w};
            #pragma unroll
            for (int i = 0; i < 8; ++i)
                #pragma unroll
                for (int j = 0; j < 8; ++j)
                    acc[i][j] = fmaf(arr[i], brr[j], acc[i][j]);
        }
    }

    // ---- epilogue: add bias (separate fp32 add, like numpy), store ----
    #pragma unroll
    for (int i = 0; i < 8; ++i) {
        const size_t r = (size_t)(bm + row0 + i);
        #pragma unroll
        for (int j = 0; j < 8; j += 4) {
            float4 v;
            v.x = __fadd_rn(acc[i][j + 0], bias[bn + col0 + j + 0]);
            v.y = __fadd_rn(acc[i][j + 1], bias[bn + col0 + j + 1]);
            v.z = __fadd_rn(acc[i][j + 2], bias[bn + col0 + j + 2]);
            v.w = __fadd_rn(acc[i][j + 3], bias[bn + col0 + j + 3]);
            *reinterpret_cast<float4*>(&C[r * GN + bn + col0 + j]) = v;
        }
    }
}

// ---------------- Phase 2: LIF scan, producer/consumer v2 ----------------
// 64 blocks; each covers 256 h-columns of one batch-half. Producer wave
// streams I_in with WIDTH-16 global_load_lds (1 KB/wave/instr, 4x fewer DMA
// instrs than R3's width-4) into a 128 KB LDS ring (128 t-slots), explicit
// s_waitcnt vmcnt(32) retirement -> 32..48 KB in flight per block x 64
// blocks ~= 2..3 MB outstanding (>= HBM BW*latency product). Consumer wave
// runs 4 independent (s,v) chains per thread from ds_read_b128.
constexpr int SH   = 256;              // h-columns per block
constexpr int SCH  = 16;               // timesteps per chunk
constexpr int NCHK = TIME / SCH;       // 64 chunks
constexpr int RT   = 128;              // ring capacity in t-slots (128 KB)
constexpr int RCH  = RT / SCH;         // 8 ring chunks

__global__ __launch_bounds__(128) void lif_scan_kernel(
    const float* __restrict__ I,   // [B, T, H]
    float* __restrict__ O)         // [B, T, H]
{
    __shared__ __align__(16) float ring[RT * SH];   // 128 KB
    __shared__ int prod_c;                 // chunks fully landed in LDS
    __shared__ int cons_c;                 // chunks consumed

    const int blk  = blockIdx.x;           // 0..63
    const int b    = blk >> 1;             // 2 blocks per batch row
    const int h0   = (blk & 1) * SH;
    const int wave = threadIdx.x >> 6;
    const int lane = threadIdx.x & 63;
    const size_t base = (size_t)b * TIME * HIDDEN + h0 + lane * 4;

    if (threadIdx.x == 0) { prod_c = 0; cons_c = 0; }
    __syncthreads();

    if (wave == 0) {
        // ---------------- producer ----------------
        const float* g0 = I + base;        // 16 B per lane, 1 KB per wave
        #pragma unroll 1
        for (int c = 0; c < NCHK; ++c) {
            if (c >= RCH) {   // slot reuse: consumer must be done with c-RCH
                while (__hip_atomic_load(&cons_c, __ATOMIC_ACQUIRE,
                                         __HIP_MEMORY_SCOPE_WORKGROUP)
                       < c - RCH + 1) { }
            }
            const int slot = (c & (RCH - 1)) * SCH;
            #pragma unroll
            for (int u = 0; u < SCH; ++u) {
                const int t = c * SCH + u;
                __builtin_amdgcn_global_load_lds(
                    (GLOBAL_AS const void*)(g0 + (size_t)t * HIDDEN),
                    (LDS_AS void*)&ring[(slot + u) * SH], 16, 0, 0);
            }
            // newest 32 DMAs = chunks c, c-1  =>  chunks <= c-2 have landed
            __builtin_amdgcn_s_waitcnt(WAITCNT_VMCNT(32));
            if (c >= 1)
                __hip_atomic_store(&prod_c, c - 1, __ATOMIC_RELEASE,
                                   __HIP_MEMORY_SCOPE_WORKGROUP);
        }
        __builtin_amdgcn_s_waitcnt(WAITCNT_VMCNT(0));
        __hip_atomic_store(&prod_c, NCHK, __ATOMIC_RELEASE,
                           __HIP_MEMORY_SCOPE_WORKGROUP);
    } else {
        // ---------------- consumer: 4 chains/thread ----------------
        // exp(-0.05), exp(-0.2) correctly rounded fp32 (match np.exp)
        const float am = 0.95122942450071400910f;
        const float as = 0.81873075307798185867f;
        float v0 = 0.f, v1 = 0.f, v2 = 0.f, v3 = 0.f;
        float s0 = 0.f, s1 = 0.f, s2 = 0.f, s3 = 0.f;
        float* o0 = O + base;

        #pragma unroll 1
        for (int c = 0; c < NCHK; ++c) {
            while (__hip_atomic_load(&prod_c, __ATOMIC_ACQUIRE,
                                     __HIP_MEMORY_SCOPE_WORKGROUP) < c + 1) { }
            const int slot = (c & (RCH - 1)) * SCH;
            #pragma unroll
            for (int u = 0; u < SCH; ++u) {
                const float4 x = *reinterpret_cast<const float4*>(
                    &ring[(slot + u) * SH + lane * 4]);
                float4 o;
                // separate mul/add roundings to match numpy (no FMA fusion)
                s0 = __fadd_rn(__fmul_rn(as, s0), x.x);
                s1 = __fadd_rn(__fmul_rn(as, s1), x.y);
                s2 = __fadd_rn(__fmul_rn(as, s2), x.z);
                s3 = __fadd_rn(__fmul_rn(as, s3), x.w);
                v0 = __fadd_rn(__fmul_rn(am, v0), s0);
                v1 = __fadd_rn(__fmul_rn(am, v1), s1);
                v2 = __fadd_rn(__fmul_rn(am, v2), s2);
                v3 = __fadd_rn(__fmul_rn(am, v3), s3);
                o.x = (v0 > 1.0f) ? 1.0f : 0.0f;
                o.y = (v1 > 1.0f) ? 1.0f : 0.0f;
                o.z = (v2 > 1.0f) ? 1.0f : 0.0f;
                o.w = (v3 > 1.0f) ? 1.0f : 0.0f;
                v0 = __fsub_rn(v0, o.x);
                v1 = __fsub_rn(v1, o.y);
                v2 = __fsub_rn(v2, o.z);
                v3 = __fsub_rn(v3, o.w);
                *reinterpret_cast<float4*>(
                    o0 + (size_t)(c * SCH + u) * HIDDEN) = o;
            }
            __hip_atomic_store(&cons_c, c + 1, __ATOMIC_RELEASE,
                               __HIP_MEMORY_SCOPE_WORKGROUP);
        }
    }
}

extern "C" void kernel_launch(void* const* d_in, const int* in_sizes, int n_in,
                              void* d_out, int out_size, void* d_ws, size_t ws_size,
                              hipStream_t stream) {
    const float* spikes = (const float*)d_in[0];   // [32, 1024, 512]
    const float* W      = (const float*)d_in[1];   // [512, 512]
    const float* bias   = (const float*)d_in[2];   // [512]
    float* out  = (float*)d_out;                   // [32, 1024, 512]
    float* I_in = (float*)d_ws;                    // 64 MiB scratch

    dim3 g1(GM / BM, GN / BN);                     // (256, 4)
    sgemm_bias_kernel<<<g1, 256, 0, stream>>>(spikes, W, bias, I_in);

    lif_scan_kernel<<<BATCH * HIDDEN / SH, 128, 0, stream>>>(I_in, out);
}